// Round 4
// baseline (150.823 us; speedup 1.0000x reference)
//
#include <hip/hip_runtime.h>

#define B_ 4
#define T_ 4096
#define E_ 1024
#define H_ 64

typedef __attribute__((ext_vector_type(8))) short short8;   // 8 x bf16 (4 VGPRs)
typedef __attribute__((ext_vector_type(4))) float f32x4;    // MFMA accumulator

static __device__ __forceinline__ unsigned short f2bf(float f) {
    unsigned int u = __builtin_bit_cast(unsigned int, f);
    u += 0x7fffu + ((u >> 16) & 1u);   // round-to-nearest-even
    return (unsigned short)(u >> 16);
}
static __device__ __forceinline__ float bf2f(unsigned short h) {
    unsigned int u = ((unsigned int)h) << 16;
    return __builtin_bit_cast(float, u);
}
// exp2 via compiler-known intrinsic: the VALU trans-op result hazard
// (1 wait state before dependent consumer) is handled by the compiler's
// hazard recognizer. Raw inline asm (round 3) hid the hazard -> corruption.
#if __has_builtin(__builtin_amdgcn_exp2f)
#define EXP2(x) __builtin_amdgcn_exp2f(x)
#else
#define EXP2(x) exp2f(x)
#endif

// ---------------------------------------------------------------------------
// Kernel 1: transpose W [1024][64] f32 -> Wt [3][64][1024] bf16
// ---------------------------------------------------------------------------
__global__ __launch_bounds__(256) void wt_transpose_kernel(
    const float* __restrict__ Wq, const float* __restrict__ Wk,
    const float* __restrict__ Wv, unsigned short* __restrict__ Wt)
{
    __shared__ float tile[64][65];
    const int mat = blockIdx.x >> 4;
    const int kt  = blockIdx.x & 15;
    const float* W = (mat == 0) ? Wq : ((mat == 1) ? Wk : Wv);
    const int tid = threadIdx.x;
    #pragma unroll
    for (int p = 0; p < 16; ++p) {
        int idx = p * 256 + tid;
        tile[idx >> 6][idx & 63] = W[(kt * 64 + (idx >> 6)) * 64 + (idx & 63)];
    }
    __syncthreads();
    #pragma unroll
    for (int p = 0; p < 16; ++p) {
        int idx = p * 256 + tid;
        int h = idx >> 6, kl = idx & 63;
        Wt[(mat * 64 + h) * E_ + kt * 64 + kl] = f2bf(tile[kl][h]);
    }
}

// ---------------------------------------------------------------------------
// Kernel 2: fused QKV projection. Q is PRE-SCALED by (1/sqrt(E))*log2(e) so
// the attention kernel can exp2() raw MFMA output with no per-element scale.
// ---------------------------------------------------------------------------
__global__ __launch_bounds__(256) void proj_kernel(
    const float* __restrict__ x, const unsigned short* __restrict__ Wt,
    unsigned short* __restrict__ Qb, unsigned short* __restrict__ Kb,
    unsigned short* __restrict__ Vt)
{
    __shared__ unsigned short wt_lds[192][72];
    const int tid  = threadIdx.x;
    const int wid  = tid >> 6, lane = tid & 63;
    const int g    = lane >> 4, c = lane & 15;
    const int r0   = blockIdx.x * 64;
    const float QSCALE = 0.03125f * 1.44269504088896f;   // 1/sqrt(1024) * log2(e)

    f32x4 acc[3][4];
    #pragma unroll
    for (int m = 0; m < 3; ++m)
        #pragma unroll
        for (int n = 0; n < 4; ++n) acc[m][n] = 0.0f;

    const float* xrow = x + (size_t)(r0 + wid * 16 + c) * E_;

    for (int kk = 0; kk < E_; kk += 64) {
        #pragma unroll
        for (int p = 0; p < 6; ++p) {
            int cidx = p * 256 + tid;
            int kchunk = cidx & 7;
            int hrow = cidx >> 3;
            *(short8*)&wt_lds[hrow][kchunk * 8] =
                *(const short8*)&Wt[hrow * E_ + kk + kchunk * 8];
        }
        __syncthreads();
        #pragma unroll
        for (int kc = 0; kc < 2; ++kc) {
            f32x4 xa = *(const f32x4*)&xrow[kk + kc * 32 + 8 * g];
            f32x4 xb = *(const f32x4*)&xrow[kk + kc * 32 + 8 * g + 4];
            short8 a;
            #pragma unroll
            for (int j = 0; j < 4; ++j) {
                a[j]     = (short)f2bf(xa[j]);
                a[j + 4] = (short)f2bf(xb[j]);
            }
            #pragma unroll
            for (int m = 0; m < 3; ++m)
                #pragma unroll
                for (int n = 0; n < 4; ++n) {
                    short8 b = *(const short8*)&wt_lds[m * 64 + n * 16 + c][kc * 32 + 8 * g];
                    acc[m][n] = __builtin_amdgcn_mfma_f32_16x16x32_bf16(a, b, acc[m][n], 0, 0, 0);
                }
        }
        __syncthreads();
    }

    const int bb = r0 >> 12;
    #pragma unroll
    for (int n = 0; n < 4; ++n)
        #pragma unroll
        for (int r = 0; r < 4; ++r) {
            int row = r0 + wid * 16 + 4 * g + r;
            int col = n * 16 + c;
            Qb[(size_t)row * H_ + col] = f2bf(acc[0][n][r] * QSCALE);
            Kb[(size_t)row * H_ + col] = f2bf(acc[1][n][r]);
            Vt[((size_t)bb * H_ + col) * T_ + (row & (T_ - 1))] = f2bf(acc[2][n][r]);
        }
}

// ---------------------------------------------------------------------------
// Kernel 3: split-K flash attention, NO-MAX exp2 softmax (shift-invariant;
// scores are tiny: s*scale ~ N(0, ~0.25), exp2 in [~0.25, ~4]).
// - no cross-lane reductions at all (the round-2 latency chain)
// - row-sum l computed by accumulating mfma(P, ones) across tiles
// - merge is a plain sum of partials
// One wave = one (q-tile, chunk of 8 kv-tiles). Same slot layout as round 2.
// ---------------------------------------------------------------------------
__global__ __launch_bounds__(256, 4) void attn_split_kernel(
    const unsigned short* __restrict__ Qb, const unsigned short* __restrict__ Kb,
    const unsigned short* __restrict__ Vt, unsigned short* __restrict__ Po,
    float* __restrict__ Pl)
{
    __shared__ unsigned short p_lds[4][16][72];
    const int tid   = threadIdx.x;
    const int wid   = tid >> 6, lane = tid & 63;
    const int g     = lane >> 4, c = lane & 15;

    const int s     = blockIdx.x * 4 + wid;      // [0, 8192)
    const int batch = s >> 11;
    const int rem   = s & 2047;
    const int ch    = rem >> 8;                  // kv-chunk [0,8)
    const int qt    = rem & 255;                 // q-tile   [0,256)
    const int nkv   = (qt >> 2) + 1;             // total kv tiles for this qt
    if (ch * 8 >= nkv) return;                   // inactive slot
    const int nt    = min(8, nkv - ch * 8);      // tiles in this chunk
    const int qbase = qt * 16;
    const int lastt = nkv - 1 - ch * 8;          // local idx of diagonal tile (if < nt)

    const int Mm = nkv - 1, aa = Mm >> 3, rr8 = Mm & 7;
    const int npart = (nkv + 7) >> 3;
    const int slot  = batch * 1152 + 4 * (4 * aa * (aa + 1) + rr8 * (aa + 1))
                    + (qt & 3) * npart + ch;

    short8 aq0, aq1;                             // Q fragments (pre-scaled)
    {
        const unsigned short* qp = Qb + ((size_t)(batch * T_ + qbase + c)) * H_ + 8 * g;
        aq0 = *(const short8*)&qp[0];
        aq1 = *(const short8*)&qp[32];
    }

    short8 ones;                                 // bf16 1.0 fragment for l-MFMA
    #pragma unroll
    for (int j = 0; j < 8; ++j) ones[j] = (short)0x3F80;

    f32x4 o_acc[4];
    #pragma unroll
    for (int n = 0; n < 4; ++n) o_acc[n] = 0.0f;
    f32x4 l_acc = 0.0f;

    const unsigned short* kp = Kb + ((size_t)(batch * T_ + ch * 512 + c)) * H_ + 8 * g;
    const unsigned short* vp = Vt + ((size_t)(batch * H_ + c)) * T_ + ch * 512 + 8 * g;

    for (int t = 0; t < nt; ++t) {
        // ---- S = Q K^T (K frags straight from L2) ----
        f32x4 sA[4];
        #pragma unroll
        for (int n = 0; n < 4; ++n) sA[n] = 0.0f;
        #pragma unroll
        for (int n = 0; n < 4; ++n) {
            short8 bk0 = *(const short8*)&kp[n * 16 * H_];
            short8 bk1 = *(const short8*)&kp[n * 16 * H_ + 32];
            sA[n] = __builtin_amdgcn_mfma_f32_16x16x32_bf16(aq0, bk0, sA[n], 0, 0, 0);
            sA[n] = __builtin_amdgcn_mfma_f32_16x16x32_bf16(aq1, bk1, sA[n], 0, 0, 0);
        }

        // ---- p = exp2(s); zero masked entries on the diagonal tile only ----
        float pv[4][4];
        #pragma unroll
        for (int n = 0; n < 4; ++n)
            #pragma unroll
            for (int r = 0; r < 4; ++r)
                pv[n][r] = EXP2(sA[n][r]);
        if (t == lastt) {                        // wave-uniform branch
            const int d = (ch * 8 + t) * 64 + c - qbase - 4 * g;
            #pragma unroll
            for (int n = 0; n < 4; ++n)
                #pragma unroll
                for (int r = 0; r < 4; ++r)
                    if (d + 16 * n > r) pv[n][r] = 0.0f;
        }

        // ---- P: D-layout -> A-frag layout via per-wave LDS (in-order DS) ----
        #pragma unroll
        for (int n = 0; n < 4; ++n)
            #pragma unroll
            for (int r = 0; r < 4; ++r)
                p_lds[wid][4 * g + r][n * 16 + c] = f2bf(pv[n][r]);
        short8 pa0 = *(const short8*)&p_lds[wid][c][8 * g];
        short8 pa1 = *(const short8*)&p_lds[wid][c][32 + 8 * g];

        // ---- l += P * 1 (free row-sum, no cross-lane ops) ----
        l_acc = __builtin_amdgcn_mfma_f32_16x16x32_bf16(pa0, ones, l_acc, 0, 0, 0);
        l_acc = __builtin_amdgcn_mfma_f32_16x16x32_bf16(pa1, ones, l_acc, 0, 0, 0);

        // ---- O += P V ----
        #pragma unroll
        for (int n = 0; n < 4; ++n) {
            short8 bv0 = *(const short8*)&vp[(size_t)n * 16 * T_];
            short8 bv1 = *(const short8*)&vp[(size_t)n * 16 * T_ + 32];
            o_acc[n] = __builtin_amdgcn_mfma_f32_16x16x32_bf16(pa0, bv0, o_acc[n], 0, 0, 0);
            o_acc[n] = __builtin_amdgcn_mfma_f32_16x16x32_bf16(pa1, bv1, o_acc[n], 0, 0, 0);
        }

        kp += 64 * H_;                           // next 64 keys
        vp += 64;
    }

    // ---- store partial: o (bf16, unnormalized), l (f32) ----
    unsigned short* po = Po + (size_t)slot * 1024;
    #pragma unroll
    for (int n = 0; n < 4; ++n)
        #pragma unroll
        for (int r = 0; r < 4; ++r)
            po[(4 * g + r) * 64 + n * 16 + c] = f2bf(o_acc[n][r]);
    if (c == 0) {
        #pragma unroll
        for (int r = 0; r < 4; ++r)
            Pl[slot * 16 + 4 * g + r] = l_acc[r];
    }
}

// ---------------------------------------------------------------------------
// Kernel 4: merge partials — plain sums (no max/exp needed in common basis).
// One wave per q-tile; lane = (row, col-segment). grid = 256 x 256.
// ---------------------------------------------------------------------------
__global__ __launch_bounds__(256) void attn_merge_kernel(
    const unsigned short* __restrict__ Po, const float* __restrict__ Pl,
    float* __restrict__ out)
{
    const int tid  = threadIdx.x;
    const int wid  = tid >> 6, lane = tid & 63;
    const int gi   = blockIdx.x * 4 + wid;       // [0, 1024)
    const int batch = gi >> 8, qt = gi & 255;
    const int nkv  = (qt >> 2) + 1;
    const int npart = (nkv + 7) >> 3;
    const int Mm = nkv - 1, aa = Mm >> 3, rr8 = Mm & 7;
    const int slot0 = batch * 1152 + 4 * (4 * aa * (aa + 1) + rr8 * (aa + 1))
                    + (qt & 3) * npart;

    const int row = lane & 15, seg = lane >> 4;

    float lacc = 0.0f, o[16];
    #pragma unroll
    for (int k = 0; k < 16; ++k) o[k] = 0.0f;

    for (int i = 0; i < npart; ++i) {
        lacc += Pl[(slot0 + i) * 16 + row];
        const unsigned short* pp = Po + (size_t)(slot0 + i) * 1024 + row * 64 + seg * 16;
        short8 v0 = *(const short8*)&pp[0];
        short8 v1 = *(const short8*)&pp[8];
        #pragma unroll
        for (int k = 0; k < 8; ++k) {
            o[k]     += bf2f((unsigned short)v0[k]);
            o[8 + k] += bf2f((unsigned short)v1[k]);
        }
    }

    const float inv = 1.0f / lacc;
    float* op = out + ((size_t)(batch * T_ + qt * 16 + row)) * H_ + seg * 16;
    #pragma unroll
    for (int k = 0; k < 16; ++k) op[k] = o[k] * inv;
}

// ---------------------------------------------------------------------------
extern "C" void kernel_launch(void* const* d_in, const int* in_sizes, int n_in,
                              void* d_out, int out_size, void* d_ws, size_t ws_size,
                              hipStream_t stream)
{
    const float* x  = (const float*)d_in[0];
    const float* Wk = (const float*)d_in[1];
    const float* Wq = (const float*)d_in[2];
    const float* Wv = (const float*)d_in[3];
    float* out = (float*)d_out;

    // workspace layout:
    //   Wt  [3*64*1024] bf16            384 KB
    //   Qb/Kb [B*T*H] bf16            2+2 MB
    //   Vt  [B*H*T] bf16                  2 MB
    //   Po  [4608][16][64] bf16         9.4 MB
    //   Pl  [4608][16] f32              295 KB   total ~16.1 MB
    unsigned short* Wt = (unsigned short*)d_ws;
    unsigned short* Qb = Wt + 3 * 64 * 1024;
    unsigned short* Kb = Qb + (size_t)B_ * T_ * H_;
    unsigned short* Vt = Kb + (size_t)B_ * T_ * H_;
    unsigned short* Po = Vt + (size_t)B_ * T_ * H_;
    float* Pl = (float*)(Po + (size_t)4608 * 1024);

    hipLaunchKernelGGL(wt_transpose_kernel, dim3(48), dim3(256), 0, stream, Wq, Wk, Wv, Wt);
    hipLaunchKernelGGL(proj_kernel, dim3(256), dim3(256), 0, stream, x, Wt, Qb, Kb, Vt);
    hipLaunchKernelGGL(attn_split_kernel, dim3(2048), dim3(256), 0, stream, Qb, Kb, Vt, Po, Pl);
    hipLaunchKernelGGL(attn_merge_kernel, dim3(256), dim3(256), 0, stream, Po, Pl, out);
}

// Round 5
// 72.943 us; speedup vs baseline: 2.0677x; 2.0677x over previous
//
#include <hip/hip_runtime.h>

#define B_ 4
#define T_ 4096
#define E_ 1024
#define H_ 64

typedef __attribute__((ext_vector_type(8))) short short8;   // 8 x bf16 (4 VGPRs)
typedef __attribute__((ext_vector_type(4))) float f32x4;    // MFMA accumulator

static __device__ __forceinline__ unsigned short f2bf(float f) {
    unsigned int u = __builtin_bit_cast(unsigned int, f);
    u += 0x7fffu + ((u >> 16) & 1u);   // round-to-nearest-even
    return (unsigned short)(u >> 16);
}
static __device__ __forceinline__ float bf2f(unsigned short h) {
    unsigned int u = ((unsigned int)h) << 16;
    return __builtin_bit_cast(float, u);
}
#if __has_builtin(__builtin_amdgcn_exp2f)
#define EXP2(x) __builtin_amdgcn_exp2f(x)
#else
#define EXP2(x) exp2f(x)
#endif

#define GLOBAL_AS __attribute__((address_space(1)))
#define LDS_AS    __attribute__((address_space(3)))

// ---------------------------------------------------------------------------
// Kernel 1: transpose W [1024][64] f32 -> Wt [3][64][1024] bf16
// ---------------------------------------------------------------------------
__global__ __launch_bounds__(256) void wt_transpose_kernel(
    const float* __restrict__ Wq, const float* __restrict__ Wk,
    const float* __restrict__ Wv, unsigned short* __restrict__ Wt)
{
    __shared__ float tile[64][65];
    const int mat = blockIdx.x >> 4;
    const int kt  = blockIdx.x & 15;
    const float* W = (mat == 0) ? Wq : ((mat == 1) ? Wk : Wv);
    const int tid = threadIdx.x;
    #pragma unroll
    for (int p = 0; p < 16; ++p) {
        int idx = p * 256 + tid;
        tile[idx >> 6][idx & 63] = W[(kt * 64 + (idx >> 6)) * 64 + (idx & 63)];
    }
    __syncthreads();
    #pragma unroll
    for (int p = 0; p < 16; ++p) {
        int idx = p * 256 + tid;
        int h = idx >> 6, kl = idx & 63;
        Wt[(mat * 64 + h) * E_ + kt * 64 + kl] = f2bf(tile[kl][h]);
    }
}

// ---------------------------------------------------------------------------
// Kernel 2: fused QKV projection. Q is PRE-SCALED by (1/sqrt(E))*log2(e).
// ---------------------------------------------------------------------------
__global__ __launch_bounds__(256) void proj_kernel(
    const float* __restrict__ x, const unsigned short* __restrict__ Wt,
    unsigned short* __restrict__ Qb, unsigned short* __restrict__ Kb,
    unsigned short* __restrict__ Vt)
{
    __shared__ unsigned short wt_lds[192][72];
    const int tid  = threadIdx.x;
    const int wid  = tid >> 6, lane = tid & 63;
    const int g    = lane >> 4, c = lane & 15;
    const int r0   = blockIdx.x * 64;
    const float QSCALE = 0.03125f * 1.44269504088896f;   // 1/sqrt(1024) * log2(e)

    f32x4 acc[3][4];
    #pragma unroll
    for (int m = 0; m < 3; ++m)
        #pragma unroll
        for (int n = 0; n < 4; ++n) acc[m][n] = 0.0f;

    const float* xrow = x + (size_t)(r0 + wid * 16 + c) * E_;

    for (int kk = 0; kk < E_; kk += 64) {
        #pragma unroll
        for (int p = 0; p < 6; ++p) {
            int cidx = p * 256 + tid;
            int kchunk = cidx & 7;
            int hrow = cidx >> 3;
            *(short8*)&wt_lds[hrow][kchunk * 8] =
                *(const short8*)&Wt[hrow * E_ + kk + kchunk * 8];
        }
        __syncthreads();
        #pragma unroll
        for (int kc = 0; kc < 2; ++kc) {
            f32x4 xa = *(const f32x4*)&xrow[kk + kc * 32 + 8 * g];
            f32x4 xb = *(const f32x4*)&xrow[kk + kc * 32 + 8 * g + 4];
            short8 a;
            #pragma unroll
            for (int j = 0; j < 4; ++j) {
                a[j]     = (short)f2bf(xa[j]);
                a[j + 4] = (short)f2bf(xb[j]);
            }
            #pragma unroll
            for (int m = 0; m < 3; ++m)
                #pragma unroll
                for (int n = 0; n < 4; ++n) {
                    short8 b = *(const short8*)&wt_lds[m * 64 + n * 16 + c][kc * 32 + 8 * g];
                    acc[m][n] = __builtin_amdgcn_mfma_f32_16x16x32_bf16(a, b, acc[m][n], 0, 0, 0);
                }
        }
        __syncthreads();
    }

    const int bb = r0 >> 12;
    #pragma unroll
    for (int n = 0; n < 4; ++n)
        #pragma unroll
        for (int r = 0; r < 4; ++r) {
            int row = r0 + wid * 16 + 4 * g + r;
            int col = n * 16 + c;
            Qb[(size_t)row * H_ + col] = f2bf(acc[0][n][r] * QSCALE);
            Kb[(size_t)row * H_ + col] = f2bf(acc[1][n][r]);
            Vt[((size_t)bb * H_ + col) * T_ + (row & (T_ - 1))] = f2bf(acc[2][n][r]);
        }
}

// ---------------------------------------------------------------------------
// Kernel 3: split-K flash attention, no-max exp2 softmax (round 4 math),
// NOW with block-shared LDS staging of K/V tiles:
// - a block's 4 waves have consecutive qt and the SAME (batch, ch) -> they
//   share every K/V tile. Round 4 loaded fragments direct from global:
//   16 lane-fragmented instructions x 16 cache lines each, x4 redundant
//   -> latency-bound at ~90% idle. Now staged ONCE per block, coalesced.
// - global_load_lds width=16, linear LDS dest; XOR chunk swizzle applied to
//   the GLOBAL source and the ds_read address (both-sides involution) so
//   fragment reads are ~2-way bank-aliased (free) instead of 4-way.
// - double-buffered: stage(t+1) issued before compute(t); ONE barrier/iter.
// Block is all-active or all-inactive; active waves share nt -> barriers safe.
// ---------------------------------------------------------------------------
__global__ __launch_bounds__(256, 3) void attn_split_kernel(
    const unsigned short* __restrict__ Qb, const unsigned short* __restrict__ Kb,
    const unsigned short* __restrict__ Vt, unsigned short* __restrict__ Po,
    float* __restrict__ Pl)
{
    __shared__ unsigned short K_lds[2][64][64];   // 16 KB (two 8 KB buffers)
    __shared__ unsigned short V_lds[2][64][64];   // 16 KB
    __shared__ unsigned short p_lds[4][16][72];   // 9 KB, per-wave P round-trip
    const int tid   = threadIdx.x;
    const int wid   = tid >> 6, lane = tid & 63;
    const int g     = lane >> 4, c = lane & 15;

    const int s     = blockIdx.x * 4 + wid;      // [0, 8192)
    const int batch = s >> 11;
    const int rem   = s & 2047;
    const int ch    = rem >> 8;                  // kv-chunk [0,8)
    const int qt    = rem & 255;                 // q-tile   [0,256)
    const int nkv   = (qt >> 2) + 1;             // total kv tiles for this qt
    if (ch * 8 >= nkv) return;                   // whole block exits together
    const int nt    = min(8, nkv - ch * 8);      // tiles in this chunk (same all waves)
    const int qbase = qt * 16;
    const int lastt = nkv - 1 - ch * 8;          // local idx of diagonal tile

    const int Mm = nkv - 1, aa = Mm >> 3, rr8 = Mm & 7;
    const int npart = (nkv + 7) >> 3;
    const int slot  = batch * 1152 + 4 * (4 * aa * (aa + 1) + rr8 * (aa + 1))
                    + (qt & 3) * npart + ch;

    // staging lane geometry: lane -> (row-in-8, chunk); swizzled source chunk
    const int rsub = lane >> 3;                  // 0..7
    const int csw  = (lane & 7) ^ rsub;          // involution chunk swizzle
    // fragment-read swizzled chunk offsets (lane-constant)
    const int cs0 = (g ^ (c & 7)) * 8;           // ushort offset of chunk g
    const int cs1 = ((g + 4) ^ (c & 7)) * 8;     // ushort offset of chunk g+4

    short8 aq0, aq1;                             // Q fragments (pre-scaled)
    {
        const unsigned short* qp = Qb + ((size_t)(batch * T_ + qbase + c)) * H_ + 8 * g;
        aq0 = *(const short8*)&qp[0];
        aq1 = *(const short8*)&qp[32];
    }

    short8 ones;                                 // bf16 1.0 fragment for l-MFMA
    #pragma unroll
    for (int j = 0; j < 8; ++j) ones[j] = (short)0x3F80;

    f32x4 o_acc[4];
    #pragma unroll
    for (int n = 0; n < 4; ++n) o_acc[n] = 0.0f;
    f32x4 l_acc = 0.0f;

    // stage K/V tile `gt` (global kv-tile index) into buffer `buf`.
    // wave w stages rows [16w, 16w+16) of each: 2 instrs K + 2 instrs V.
    auto stage = [&](int buf, int gt) {
        const int key0 = gt * 64;
        #pragma unroll
        for (int j = 0; j < 2; ++j) {
            const int row = wid * 16 + j * 8;    // tile row base (mult of 8)
            const unsigned short* gk = Kb
                + ((size_t)(batch * T_ + key0 + row + rsub)) * H_ + csw * 8;
            __builtin_amdgcn_global_load_lds(
                (const GLOBAL_AS unsigned int*)gk,
                (LDS_AS unsigned int*)&K_lds[buf][row][0], 16, 0, 0);
            const unsigned short* gv = Vt
                + ((size_t)(batch * H_ + row + rsub)) * T_ + key0 + csw * 8;
            __builtin_amdgcn_global_load_lds(
                (const GLOBAL_AS unsigned int*)gv,
                (LDS_AS unsigned int*)&V_lds[buf][row][0], 16, 0, 0);
        }
    };

    stage(0, ch * 8);
    __syncthreads();                             // vmcnt drain + barrier

    for (int t = 0; t < nt; ++t) {
        const int buf = t & 1;
        if (t + 1 < nt) stage(buf ^ 1, ch * 8 + t + 1);

        // ---- S = Q K^T (K frags from LDS, swizzled chunks) ----
        f32x4 sA[4];
        #pragma unroll
        for (int n = 0; n < 4; ++n) sA[n] = 0.0f;
        #pragma unroll
        for (int n = 0; n < 4; ++n) {
            short8 bk0 = *(const short8*)&K_lds[buf][n * 16 + c][cs0];
            short8 bk1 = *(const short8*)&K_lds[buf][n * 16 + c][cs1];
            sA[n] = __builtin_amdgcn_mfma_f32_16x16x32_bf16(aq0, bk0, sA[n], 0, 0, 0);
            sA[n] = __builtin_amdgcn_mfma_f32_16x16x32_bf16(aq1, bk1, sA[n], 0, 0, 0);
        }

        // ---- p = exp2(s); mask only the diagonal tile ----
        float pv[4][4];
        #pragma unroll
        for (int n = 0; n < 4; ++n)
            #pragma unroll
            for (int r = 0; r < 4; ++r)
                pv[n][r] = EXP2(sA[n][r]);
        if (t == lastt) {                        // wave-uniform branch
            const int d = (ch * 8 + t) * 64 + c - qbase - 4 * g;
            #pragma unroll
            for (int n = 0; n < 4; ++n)
                #pragma unroll
                for (int r = 0; r < 4; ++r)
                    if (d + 16 * n > r) pv[n][r] = 0.0f;
        }

        // ---- P: D-layout -> A-frag layout via per-wave LDS ----
        #pragma unroll
        for (int n = 0; n < 4; ++n)
            #pragma unroll
            for (int r = 0; r < 4; ++r)
                p_lds[wid][4 * g + r][n * 16 + c] = f2bf(pv[n][r]);
        short8 pa0 = *(const short8*)&p_lds[wid][c][8 * g];
        short8 pa1 = *(const short8*)&p_lds[wid][c][32 + 8 * g];

        // ---- l += P * 1 ----
        l_acc = __builtin_amdgcn_mfma_f32_16x16x32_bf16(pa0, ones, l_acc, 0, 0, 0);
        l_acc = __builtin_amdgcn_mfma_f32_16x16x32_bf16(pa1, ones, l_acc, 0, 0, 0);

        // ---- O += P V (V frags from LDS, swizzled chunks) ----
        #pragma unroll
        for (int n = 0; n < 4; ++n) {
            short8 bv0 = *(const short8*)&V_lds[buf][n * 16 + c][cs0];
            short8 bv1 = *(const short8*)&V_lds[buf][n * 16 + c][cs1];
            o_acc[n] = __builtin_amdgcn_mfma_f32_16x16x32_bf16(pa0, bv0, o_acc[n], 0, 0, 0);
            o_acc[n] = __builtin_amdgcn_mfma_f32_16x16x32_bf16(pa1, bv1, o_acc[n], 0, 0, 0);
        }

        __syncthreads();                         // staged t+1 landed; buf free
    }

    // ---- store partial: o (bf16, unnormalized), l (f32) ----
    unsigned short* po = Po + (size_t)slot * 1024;
    #pragma unroll
    for (int n = 0; n < 4; ++n)
        #pragma unroll
        for (int r = 0; r < 4; ++r)
            po[(4 * g + r) * 64 + n * 16 + c] = f2bf(o_acc[n][r]);
    if (c == 0) {
        #pragma unroll
        for (int r = 0; r < 4; ++r)
            Pl[slot * 16 + 4 * g + r] = l_acc[r];
    }
}

// ---------------------------------------------------------------------------
// Kernel 4: merge partials — plain sums. One wave per q-tile.
// ---------------------------------------------------------------------------
__global__ __launch_bounds__(256) void attn_merge_kernel(
    const unsigned short* __restrict__ Po, const float* __restrict__ Pl,
    float* __restrict__ out)
{
    const int tid  = threadIdx.x;
    const int wid  = tid >> 6, lane = tid & 63;
    const int gi   = blockIdx.x * 4 + wid;       // [0, 1024)
    const int batch = gi >> 8, qt = gi & 255;
    const int nkv  = (qt >> 2) + 1;
    const int npart = (nkv + 7) >> 3;
    const int Mm = nkv - 1, aa = Mm >> 3, rr8 = Mm & 7;
    const int slot0 = batch * 1152 + 4 * (4 * aa * (aa + 1) + rr8 * (aa + 1))
                    + (qt & 3) * npart;

    const int row = lane & 15, seg = lane >> 4;

    float lacc = 0.0f, o[16];
    #pragma unroll
    for (int k = 0; k < 16; ++k) o[k] = 0.0f;

    for (int i = 0; i < npart; ++i) {
        lacc += Pl[(slot0 + i) * 16 + row];
        const unsigned short* pp = Po + (size_t)(slot0 + i) * 1024 + row * 64 + seg * 16;
        short8 v0 = *(const short8*)&pp[0];
        short8 v1 = *(const short8*)&pp[8];
        #pragma unroll
        for (int k = 0; k < 8; ++k) {
            o[k]     += bf2f((unsigned short)v0[k]);
            o[8 + k] += bf2f((unsigned short)v1[k]);
        }
    }

    const float inv = 1.0f / lacc;
    float* op = out + ((size_t)(batch * T_ + qt * 16 + row)) * H_ + seg * 16;
    #pragma unroll
    for (int k = 0; k < 16; ++k) op[k] = o[k] * inv;
}

// ---------------------------------------------------------------------------
extern "C" void kernel_launch(void* const* d_in, const int* in_sizes, int n_in,
                              void* d_out, int out_size, void* d_ws, size_t ws_size,
                              hipStream_t stream)
{
    const float* x  = (const float*)d_in[0];
    const float* Wk = (const float*)d_in[1];
    const float* Wq = (const float*)d_in[2];
    const float* Wv = (const float*)d_in[3];
    float* out = (float*)d_out;

    // workspace layout:
    //   Wt  [3*64*1024] bf16            384 KB
    //   Qb/Kb [B*T*H] bf16            2+2 MB
    //   Vt  [B*H*T] bf16                  2 MB
    //   Po  [4608][16][64] bf16         9.4 MB
    //   Pl  [4608][16] f32              295 KB   total ~16.1 MB
    unsigned short* Wt = (unsigned short*)d_ws;
    unsigned short* Qb = Wt + 3 * 64 * 1024;
    unsigned short* Kb = Qb + (size_t)B_ * T_ * H_;
    unsigned short* Vt = Kb + (size_t)B_ * T_ * H_;
    unsigned short* Po = Vt + (size_t)B_ * T_ * H_;
    float* Pl = (float*)(Po + (size_t)4608 * 1024);

    hipLaunchKernelGGL(wt_transpose_kernel, dim3(48), dim3(256), 0, stream, Wq, Wk, Wv, Wt);
    hipLaunchKernelGGL(proj_kernel, dim3(256), dim3(256), 0, stream, x, Wt, Qb, Kb, Vt);
    hipLaunchKernelGGL(attn_split_kernel, dim3(2048), dim3(256), 0, stream, Qb, Kb, Vt, Po, Pl);
    hipLaunchKernelGGL(attn_merge_kernel, dim3(256), dim3(256), 0, stream, Po, Pl, out);
}

// Round 6
// 67.940 us; speedup vs baseline: 2.2199x; 1.0736x over previous
//
#include <hip/hip_runtime.h>

#define B_ 4
#define T_ 4096
#define E_ 1024
#define H_ 64

typedef __attribute__((ext_vector_type(8))) short short8;   // 8 x bf16 (4 VGPRs)
typedef __attribute__((ext_vector_type(4))) float f32x4;    // MFMA accumulator

static __device__ __forceinline__ unsigned short f2bf(float f) {
    unsigned int u = __builtin_bit_cast(unsigned int, f);
    u += 0x7fffu + ((u >> 16) & 1u);   // round-to-nearest-even
    return (unsigned short)(u >> 16);
}
static __device__ __forceinline__ float bf2f(unsigned short h) {
    unsigned int u = ((unsigned int)h) << 16;
    return __builtin_bit_cast(float, u);
}
#if __has_builtin(__builtin_amdgcn_exp2f)
#define EXP2(x) __builtin_amdgcn_exp2f(x)
#else
#define EXP2(x) exp2f(x)
#endif

#define GLOBAL_AS __attribute__((address_space(1)))
#define LDS_AS    __attribute__((address_space(3)))

// ---------------------------------------------------------------------------
// Kernel 1: transpose W [1024][64] f32 -> Wt [3][64][1024] bf16
// ---------------------------------------------------------------------------
__global__ __launch_bounds__(256) void wt_transpose_kernel(
    const float* __restrict__ Wq, const float* __restrict__ Wk,
    const float* __restrict__ Wv, unsigned short* __restrict__ Wt)
{
    __shared__ float tile[64][65];
    const int mat = blockIdx.x >> 4;
    const int kt  = blockIdx.x & 15;
    const float* W = (mat == 0) ? Wq : ((mat == 1) ? Wk : Wv);
    const int tid = threadIdx.x;
    #pragma unroll
    for (int p = 0; p < 16; ++p) {
        int idx = p * 256 + tid;
        tile[idx >> 6][idx & 63] = W[(kt * 64 + (idx >> 6)) * 64 + (idx & 63)];
    }
    __syncthreads();
    #pragma unroll
    for (int p = 0; p < 16; ++p) {
        int idx = p * 256 + tid;
        int h = idx >> 6, kl = idx & 63;
        Wt[(mat * 64 + h) * E_ + kt * 64 + kl] = f2bf(tile[kl][h]);
    }
}

// ---------------------------------------------------------------------------
// Kernel 2: fused QKV projection, ROUND-5-RECIPE REWRITE.
// Round 5 profile: 42 us, all pipes idle (MFMA 5%, VALU 6%, HBM 12%,
// occ 9.6%) -> latency-bound at 1 wave/SIMD with fragmented x loads and a
// reg-round-trip Wt stage. Now:
//  - 768-thread blocks: 12 waves = 3 mats x 4 row-groups; 3 waves/SIMD.
//  - x (64x64 f32, 16 KB) AND Wt (192x64 bf16, 24 KB) staged per 64-K chunk
//    via global_load_lds width=16, double-buffered, ONE barrier/iter.
//  - XOR chunk swizzle, both-sides (inverse-swizzled global src, swizzled
//    ds_read chunk): x rows stride 256B and Wt rows stride 128B would be
//    16-way bank conflicts unswizzled; swizzled -> 2-way (free).
// Q is pre-scaled by (1/sqrt(E))*log2(e) for the attention exp2.
// ---------------------------------------------------------------------------
__global__ __launch_bounds__(768, 1) void proj_kernel(
    const float* __restrict__ x, const unsigned short* __restrict__ Wt,
    unsigned short* __restrict__ Qb, unsigned short* __restrict__ Kb,
    unsigned short* __restrict__ Vt)
{
    __shared__ float          x_lds[2][4096];    // 64 rows x 64 f32 (swizzled chunks)
    __shared__ unsigned short wt_lds[2][12288];  // 192 rows x 64 bf16 (swizzled chunks)
    const int tid  = threadIdx.x;
    const int wid  = tid >> 6, lane = tid & 63;
    const int g    = lane >> 4, c = lane & 15;
    const int mat  = wid >> 2;                   // 0=Q 1=K 2=V
    const int rg   = wid & 3;                    // 16-row group within block
    const int r0   = blockIdx.x * 64;
    const float QSCALE = 0.03125f * 1.44269504088896f;   // 1/sqrt(1024)*log2(e)

    // stage x[64 rows][kk..kk+64] and Wt[192 rows][kk..kk+64] into buffer buf.
    // 16B chunk idx -> (row, chunk); global src chunk = chunk ^ (row & mask)
    // (involution); LDS dest linear in idx (wave-uniform base + lane*16).
    auto stage = [&](int buf, int kk) {
        {   // x: 1024 chunks (16 f32-chunks per row)
            int row = tid >> 4, ch = tid & 15;
            int csw = ch ^ (row & 15);
            const float* src = x + (size_t)(r0 + row) * E_ + kk + csw * 4;
            __builtin_amdgcn_global_load_lds(
                (const GLOBAL_AS unsigned int*)src,
                (LDS_AS unsigned int*)&x_lds[buf][(tid & ~63) * 4], 16, 0, 0);
            if (tid < 256) {                     // waves 0..3: chunks 768..1023
                int idx2 = 768 + tid;
                int row2 = idx2 >> 4, ch2 = idx2 & 15;
                int csw2 = ch2 ^ (row2 & 15);
                const float* src2 = x + (size_t)(r0 + row2) * E_ + kk + csw2 * 4;
                __builtin_amdgcn_global_load_lds(
                    (const GLOBAL_AS unsigned int*)src2,
                    (LDS_AS unsigned int*)&x_lds[buf][(idx2 & ~63) * 4], 16, 0, 0);
            }
        }
        #pragma unroll
        for (int p = 0; p < 2; ++p) {            // Wt: 1536 chunks (8 per row)
            int idx = p * 768 + tid;
            int row = idx >> 3, ch = idx & 7;
            int csw = ch ^ (row & 7);
            const unsigned short* src = Wt + (size_t)row * E_ + kk + csw * 8;
            __builtin_amdgcn_global_load_lds(
                (const GLOBAL_AS unsigned int*)src,
                (LDS_AS unsigned int*)&wt_lds[buf][(idx & ~63) * 8], 16, 0, 0);
        }
    };

    f32x4 acc[4];
    #pragma unroll
    for (int n = 0; n < 4; ++n) acc[n] = 0.0f;

    stage(0, 0);
    __syncthreads();

    for (int t = 0; t < 16; ++t) {
        const int buf = t & 1;
        if (t < 15) stage(buf ^ 1, (t + 1) * 64);

        const int xrowbase = (rg * 16 + c) * 64;
        const int wrowbase = (mat * 64 + c) * 64;    // + n*16*64 added per n
        #pragma unroll
        for (int kc = 0; kc < 2; ++kc) {
            // A fragment: row rg*16+c, k = kc*32 + 8g .. +8 (chunks 8kc+2g, +1)
            f32x4 xa = *(const f32x4*)&x_lds[buf][xrowbase + ((8 * kc + 2 * g)     ^ c) * 4];
            f32x4 xb = *(const f32x4*)&x_lds[buf][xrowbase + ((8 * kc + 2 * g + 1) ^ c) * 4];
            short8 a;
            #pragma unroll
            for (int j = 0; j < 4; ++j) {
                a[j]     = (short)f2bf(xa[j]);
                a[j + 4] = (short)f2bf(xb[j]);
            }
            // B fragments: Wt row mat*64+n*16+c, k chunk 4kc+g (swizzled)
            #pragma unroll
            for (int n = 0; n < 4; ++n) {
                short8 b = *(const short8*)
                    &wt_lds[buf][wrowbase + n * 1024 + (((4 * kc + g) ^ (c & 7)) * 8)];
                acc[n] = __builtin_amdgcn_mfma_f32_16x16x32_bf16(a, b, acc[n], 0, 0, 0);
            }
        }
        __syncthreads();
    }

    const int bb = r0 >> 12;                     // batch (no block straddles)
    #pragma unroll
    for (int n = 0; n < 4; ++n)
        #pragma unroll
        for (int r = 0; r < 4; ++r) {
            int row = r0 + rg * 16 + 4 * g + r;
            int col = n * 16 + c;
            float v = acc[n][r];
            if (mat == 0)
                Qb[(size_t)row * H_ + col] = f2bf(v * QSCALE);
            else if (mat == 1)
                Kb[(size_t)row * H_ + col] = f2bf(v);
            else
                Vt[((size_t)bb * H_ + col) * T_ + (row & (T_ - 1))] = f2bf(v);
        }
}

// ---------------------------------------------------------------------------
// Kernel 3: split-K flash attention (round-5 version, unchanged).
// ---------------------------------------------------------------------------
__global__ __launch_bounds__(256, 3) void attn_split_kernel(
    const unsigned short* __restrict__ Qb, const unsigned short* __restrict__ Kb,
    const unsigned short* __restrict__ Vt, unsigned short* __restrict__ Po,
    float* __restrict__ Pl)
{
    __shared__ unsigned short K_lds[2][64][64];   // 16 KB (two 8 KB buffers)
    __shared__ unsigned short V_lds[2][64][64];   // 16 KB
    __shared__ unsigned short p_lds[4][16][72];   // 9 KB, per-wave P round-trip
    const int tid   = threadIdx.x;
    const int wid   = tid >> 6, lane = tid & 63;
    const int g     = lane >> 4, c = lane & 15;

    const int s     = blockIdx.x * 4 + wid;      // [0, 8192)
    const int batch = s >> 11;
    const int rem   = s & 2047;
    const int ch    = rem >> 8;                  // kv-chunk [0,8)
    const int qt    = rem & 255;                 // q-tile   [0,256)
    const int nkv   = (qt >> 2) + 1;             // total kv tiles for this qt
    if (ch * 8 >= nkv) return;                   // whole block exits together
    const int nt    = min(8, nkv - ch * 8);      // tiles in this chunk (same all waves)
    const int qbase = qt * 16;
    const int lastt = nkv - 1 - ch * 8;          // local idx of diagonal tile

    const int Mm = nkv - 1, aa = Mm >> 3, rr8 = Mm & 7;
    const int npart = (nkv + 7) >> 3;
    const int slot  = batch * 1152 + 4 * (4 * aa * (aa + 1) + rr8 * (aa + 1))
                    + (qt & 3) * npart + ch;

    const int rsub = lane >> 3;                  // staging: row-in-8
    const int csw  = (lane & 7) ^ rsub;          // involution chunk swizzle
    const int cs0 = (g ^ (c & 7)) * 8;           // read chunk offsets (lane-const)
    const int cs1 = ((g + 4) ^ (c & 7)) * 8;

    short8 aq0, aq1;                             // Q fragments (pre-scaled)
    {
        const unsigned short* qp = Qb + ((size_t)(batch * T_ + qbase + c)) * H_ + 8 * g;
        aq0 = *(const short8*)&qp[0];
        aq1 = *(const short8*)&qp[32];
    }

    short8 ones;                                 // bf16 1.0 fragment for l-MFMA
    #pragma unroll
    for (int j = 0; j < 8; ++j) ones[j] = (short)0x3F80;

    f32x4 o_acc[4];
    #pragma unroll
    for (int n = 0; n < 4; ++n) o_acc[n] = 0.0f;
    f32x4 l_acc = 0.0f;

    auto stage = [&](int buf, int gt) {
        const int key0 = gt * 64;
        #pragma unroll
        for (int j = 0; j < 2; ++j) {
            const int row = wid * 16 + j * 8;
            const unsigned short* gk = Kb
                + ((size_t)(batch * T_ + key0 + row + rsub)) * H_ + csw * 8;
            __builtin_amdgcn_global_load_lds(
                (const GLOBAL_AS unsigned int*)gk,
                (LDS_AS unsigned int*)&K_lds[buf][row][0], 16, 0, 0);
            const unsigned short* gv = Vt
                + ((size_t)(batch * H_ + row + rsub)) * T_ + key0 + csw * 8;
            __builtin_amdgcn_global_load_lds(
                (const GLOBAL_AS unsigned int*)gv,
                (LDS_AS unsigned int*)&V_lds[buf][row][0], 16, 0, 0);
        }
    };

    stage(0, ch * 8);
    __syncthreads();

    for (int t = 0; t < nt; ++t) {
        const int buf = t & 1;
        if (t + 1 < nt) stage(buf ^ 1, ch * 8 + t + 1);

        // ---- S = Q K^T (K frags from LDS, swizzled chunks) ----
        f32x4 sA[4];
        #pragma unroll
        for (int n = 0; n < 4; ++n) sA[n] = 0.0f;
        #pragma unroll
        for (int n = 0; n < 4; ++n) {
            short8 bk0 = *(const short8*)&K_lds[buf][n * 16 + c][cs0];
            short8 bk1 = *(const short8*)&K_lds[buf][n * 16 + c][cs1];
            sA[n] = __builtin_amdgcn_mfma_f32_16x16x32_bf16(aq0, bk0, sA[n], 0, 0, 0);
            sA[n] = __builtin_amdgcn_mfma_f32_16x16x32_bf16(aq1, bk1, sA[n], 0, 0, 0);
        }

        // ---- p = exp2(s); mask only the diagonal tile ----
        float pv[4][4];
        #pragma unroll
        for (int n = 0; n < 4; ++n)
            #pragma unroll
            for (int r = 0; r < 4; ++r)
                pv[n][r] = EXP2(sA[n][r]);
        if (t == lastt) {                        // wave-uniform branch
            const int d = (ch * 8 + t) * 64 + c - qbase - 4 * g;
            #pragma unroll
            for (int n = 0; n < 4; ++n)
                #pragma unroll
                for (int r = 0; r < 4; ++r)
                    if (d + 16 * n > r) pv[n][r] = 0.0f;
        }

        // ---- P: D-layout -> A-frag layout via per-wave LDS ----
        #pragma unroll
        for (int n = 0; n < 4; ++n)
            #pragma unroll
            for (int r = 0; r < 4; ++r)
                p_lds[wid][4 * g + r][n * 16 + c] = f2bf(pv[n][r]);
        short8 pa0 = *(const short8*)&p_lds[wid][c][8 * g];
        short8 pa1 = *(const short8*)&p_lds[wid][c][32 + 8 * g];

        // ---- l += P * 1 ----
        l_acc = __builtin_amdgcn_mfma_f32_16x16x32_bf16(pa0, ones, l_acc, 0, 0, 0);
        l_acc = __builtin_amdgcn_mfma_f32_16x16x32_bf16(pa1, ones, l_acc, 0, 0, 0);

        // ---- O += P V (V frags from LDS, swizzled chunks) ----
        #pragma unroll
        for (int n = 0; n < 4; ++n) {
            short8 bv0 = *(const short8*)&V_lds[buf][n * 16 + c][cs0];
            short8 bv1 = *(const short8*)&V_lds[buf][n * 16 + c][cs1];
            o_acc[n] = __builtin_amdgcn_mfma_f32_16x16x32_bf16(pa0, bv0, o_acc[n], 0, 0, 0);
            o_acc[n] = __builtin_amdgcn_mfma_f32_16x16x32_bf16(pa1, bv1, o_acc[n], 0, 0, 0);
        }

        __syncthreads();
    }

    unsigned short* po = Po + (size_t)slot * 1024;
    #pragma unroll
    for (int n = 0; n < 4; ++n)
        #pragma unroll
        for (int r = 0; r < 4; ++r)
            po[(4 * g + r) * 64 + n * 16 + c] = f2bf(o_acc[n][r]);
    if (c == 0) {
        #pragma unroll
        for (int r = 0; r < 4; ++r)
            Pl[slot * 16 + 4 * g + r] = l_acc[r];
    }
}

// ---------------------------------------------------------------------------
// Kernel 4: merge partials — plain sums. One wave per q-tile.
// ---------------------------------------------------------------------------
__global__ __launch_bounds__(256) void attn_merge_kernel(
    const unsigned short* __restrict__ Po, const float* __restrict__ Pl,
    float* __restrict__ out)
{
    const int tid  = threadIdx.x;
    const int wid  = tid >> 6, lane = tid & 63;
    const int gi   = blockIdx.x * 4 + wid;       // [0, 1024)
    const int batch = gi >> 8, qt = gi & 255;
    const int nkv  = (qt >> 2) + 1;
    const int npart = (nkv + 7) >> 3;
    const int Mm = nkv - 1, aa = Mm >> 3, rr8 = Mm & 7;
    const int slot0 = batch * 1152 + 4 * (4 * aa * (aa + 1) + rr8 * (aa + 1))
                    + (qt & 3) * npart;

    const int row = lane & 15, seg = lane >> 4;

    float lacc = 0.0f, o[16];
    #pragma unroll
    for (int k = 0; k < 16; ++k) o[k] = 0.0f;

    for (int i = 0; i < npart; ++i) {
        lacc += Pl[(slot0 + i) * 16 + row];
        const unsigned short* pp = Po + (size_t)(slot0 + i) * 1024 + row * 64 + seg * 16;
        short8 v0 = *(const short8*)&pp[0];
        short8 v1 = *(const short8*)&pp[8];
        #pragma unroll
        for (int k = 0; k < 8; ++k) {
            o[k]     += bf2f((unsigned short)v0[k]);
            o[8 + k] += bf2f((unsigned short)v1[k]);
        }
    }

    const float inv = 1.0f / lacc;
    float* op = out + ((size_t)(batch * T_ + qt * 16 + row)) * H_ + seg * 16;
    #pragma unroll
    for (int k = 0; k < 16; ++k) op[k] = o[k] * inv;
}

// ---------------------------------------------------------------------------
extern "C" void kernel_launch(void* const* d_in, const int* in_sizes, int n_in,
                              void* d_out, int out_size, void* d_ws, size_t ws_size,
                              hipStream_t stream)
{
    const float* x  = (const float*)d_in[0];
    const float* Wk = (const float*)d_in[1];
    const float* Wq = (const float*)d_in[2];
    const float* Wv = (const float*)d_in[3];
    float* out = (float*)d_out;

    // workspace layout:
    //   Wt  [3*64*1024] bf16            384 KB
    //   Qb/Kb [B*T*H] bf16            2+2 MB
    //   Vt  [B*H*T] bf16                  2 MB
    //   Po  [4608][16][64] bf16         9.4 MB
    //   Pl  [4608][16] f32              295 KB   total ~16.1 MB
    unsigned short* Wt = (unsigned short*)d_ws;
    unsigned short* Qb = Wt + 3 * 64 * 1024;
    unsigned short* Kb = Qb + (size_t)B_ * T_ * H_;
    unsigned short* Vt = Kb + (size_t)B_ * T_ * H_;
    unsigned short* Po = Vt + (size_t)B_ * T_ * H_;
    float* Pl = (float*)(Po + (size_t)4608 * 1024);

    hipLaunchKernelGGL(wt_transpose_kernel, dim3(48), dim3(256), 0, stream, Wq, Wk, Wv, Wt);
    hipLaunchKernelGGL(proj_kernel, dim3(256), dim3(768), 0, stream, x, Wt, Qb, Kb, Vt);
    hipLaunchKernelGGL(attn_split_kernel, dim3(2048), dim3(256), 0, stream, Qb, Kb, Vt, Po, Pl);
    hipLaunchKernelGGL(attn_merge_kernel, dim3(256), dim3(256), 0, stream, Po, Pl, out);
}

// Round 7
// 67.574 us; speedup vs baseline: 2.2320x; 1.0054x over previous
//
#include <hip/hip_runtime.h>

#define B_ 4
#define T_ 4096
#define E_ 1024
#define H_ 64

typedef __attribute__((ext_vector_type(8))) short short8;   // 8 x bf16 (4 VGPRs)
typedef __attribute__((ext_vector_type(4))) float f32x4;    // MFMA accumulator

static __device__ __forceinline__ unsigned short f2bf(float f) {
    unsigned int u = __builtin_bit_cast(unsigned int, f);
    u += 0x7fffu + ((u >> 16) & 1u);   // round-to-nearest-even
    return (unsigned short)(u >> 16);
}
static __device__ __forceinline__ float bf2f(unsigned short h) {
    unsigned int u = ((unsigned int)h) << 16;
    return __builtin_bit_cast(float, u);
}
#if __has_builtin(__builtin_amdgcn_exp2f)
#define EXP2(x) __builtin_amdgcn_exp2f(x)
#else
#define EXP2(x) exp2f(x)
#endif

#define GLOBAL_AS __attribute__((address_space(1)))
#define LDS_AS    __attribute__((address_space(3)))

// ---------------------------------------------------------------------------
// Kernel 1: transpose W [1024][64] f32 -> Wt [3][64][1024] bf16
// ---------------------------------------------------------------------------
__global__ __launch_bounds__(256) void wt_transpose_kernel(
    const float* __restrict__ Wq, const float* __restrict__ Wk,
    const float* __restrict__ Wv, unsigned short* __restrict__ Wt)
{
    __shared__ float tile[64][65];
    const int mat = blockIdx.x >> 4;
    const int kt  = blockIdx.x & 15;
    const float* W = (mat == 0) ? Wq : ((mat == 1) ? Wk : Wv);
    const int tid = threadIdx.x;
    #pragma unroll
    for (int p = 0; p < 16; ++p) {
        int idx = p * 256 + tid;
        tile[idx >> 6][idx & 63] = W[(kt * 64 + (idx >> 6)) * 64 + (idx & 63)];
    }
    __syncthreads();
    #pragma unroll
    for (int p = 0; p < 16; ++p) {
        int idx = p * 256 + tid;
        int h = idx >> 6, kl = idx & 63;
        Wt[(mat * 64 + h) * E_ + kt * 64 + kl] = f2bf(tile[kl][h]);
    }
}

// ---------------------------------------------------------------------------
// Kernel 2: fused QKV projection.
// proj has been 37-42us across SIX structural rewrites -> the invariant was
// the bottleneck: the epilogue's scattered 2-byte stores (V transpose: 16
// lanes x 2B at 8KB stride = 16 cache lines PER STORE, x16 stores/thread).
// NOW: accumulators -> LDS tiles (V transposed at LDS-write, 2-way bank =
// free) -> one barrier -> 768 threads store Q/K/V as contiguous short8
// chunks (each wave store = 1KB contiguous). 8x fewer store instrs, ~16-32x
// fewer cache sectors on V.
// Staging (round 6): x+Wt per 64-K chunk via global_load_lds w=16, double-
// buffered, both-sides XOR chunk swizzle. Q pre-scaled by (1/sqrt(E))log2(e).
// ---------------------------------------------------------------------------
__global__ __launch_bounds__(768, 1) void proj_kernel(
    const float* __restrict__ x, const unsigned short* __restrict__ Wt,
    unsigned short* __restrict__ Qb, unsigned short* __restrict__ Kb,
    unsigned short* __restrict__ Vt)
{
    __shared__ float          x_lds[2][4096];    // 64 rows x 64 f32 (swizzled chunks)
    __shared__ unsigned short wt_lds[2][12288];  // 192 rows x 64 bf16 (swizzled chunks)
    __shared__ __align__(16) unsigned short ep[3][64][72];  // epilogue tiles (27 KB)
    const int tid  = threadIdx.x;
    const int wid  = tid >> 6, lane = tid & 63;
    const int g    = lane >> 4, c = lane & 15;
    const int mat  = wid >> 2;                   // 0=Q 1=K 2=V
    const int rg   = wid & 3;                    // 16-row group within block
    const int r0   = blockIdx.x * 64;
    const float QSCALE = 0.03125f * 1.44269504088896f;   // 1/sqrt(1024)*log2(e)

    auto stage = [&](int buf, int kk) {
        {   // x: 1024 chunks (16 f32-chunks per row)
            int row = tid >> 4, ch = tid & 15;
            int csw = ch ^ (row & 15);
            const float* src = x + (size_t)(r0 + row) * E_ + kk + csw * 4;
            __builtin_amdgcn_global_load_lds(
                (const GLOBAL_AS unsigned int*)src,
                (LDS_AS unsigned int*)&x_lds[buf][(tid & ~63) * 4], 16, 0, 0);
            if (tid < 256) {                     // waves 0..3: chunks 768..1023
                int idx2 = 768 + tid;
                int row2 = idx2 >> 4, ch2 = idx2 & 15;
                int csw2 = ch2 ^ (row2 & 15);
                const float* src2 = x + (size_t)(r0 + row2) * E_ + kk + csw2 * 4;
                __builtin_amdgcn_global_load_lds(
                    (const GLOBAL_AS unsigned int*)src2,
                    (LDS_AS unsigned int*)&x_lds[buf][(idx2 & ~63) * 4], 16, 0, 0);
            }
        }
        #pragma unroll
        for (int p = 0; p < 2; ++p) {            // Wt: 1536 chunks (8 per row)
            int idx = p * 768 + tid;
            int row = idx >> 3, ch = idx & 7;
            int csw = ch ^ (row & 7);
            const unsigned short* src = Wt + (size_t)row * E_ + kk + csw * 8;
            __builtin_amdgcn_global_load_lds(
                (const GLOBAL_AS unsigned int*)src,
                (LDS_AS unsigned int*)&wt_lds[buf][(idx & ~63) * 8], 16, 0, 0);
        }
    };

    f32x4 acc[4];
    #pragma unroll
    for (int n = 0; n < 4; ++n) acc[n] = 0.0f;

    stage(0, 0);
    __syncthreads();

    for (int t = 0; t < 16; ++t) {
        const int buf = t & 1;
        if (t < 15) stage(buf ^ 1, (t + 1) * 64);

        const int xrowbase = (rg * 16 + c) * 64;
        const int wrowbase = (mat * 64 + c) * 64;
        #pragma unroll
        for (int kc = 0; kc < 2; ++kc) {
            f32x4 xa = *(const f32x4*)&x_lds[buf][xrowbase + ((8 * kc + 2 * g)     ^ c) * 4];
            f32x4 xb = *(const f32x4*)&x_lds[buf][xrowbase + ((8 * kc + 2 * g + 1) ^ c) * 4];
            short8 a;
            #pragma unroll
            for (int j = 0; j < 4; ++j) {
                a[j]     = (short)f2bf(xa[j]);
                a[j + 4] = (short)f2bf(xb[j]);
            }
            #pragma unroll
            for (int n = 0; n < 4; ++n) {
                short8 b = *(const short8*)
                    &wt_lds[buf][wrowbase + n * 1024 + (((4 * kc + g) ^ (c & 7)) * 8)];
                acc[n] = __builtin_amdgcn_mfma_f32_16x16x32_bf16(a, b, acc[n], 0, 0, 0);
            }
        }
        __syncthreads();
    }

    // ---- epilogue: acc -> LDS tiles (V transposed), then coalesced stores ----
    #pragma unroll
    for (int n = 0; n < 4; ++n)
        #pragma unroll
        for (int r = 0; r < 4; ++r) {
            const int row = rg * 16 + 4 * g + r;   // row within 64-row block
            const int col = n * 16 + c;
            if (mat == 0)      ep[0][row][col] = f2bf(acc[n][r] * QSCALE);
            else if (mat == 1) ep[1][row][col] = f2bf(acc[n][r]);
            else               ep[2][col][row] = f2bf(acc[n][r]);   // transposed
        }
    __syncthreads();

    const int bb   = r0 >> 12;                   // batch (blocks don't straddle)
    const int rloc = r0 & (T_ - 1);              // row offset within batch
    #pragma unroll
    for (int it = 0; it < 2; ++it) {
        int idx = it * 768 + tid;                // 0..1535 = 3 mats x 64 rows x 8 chunks
        int m2  = idx >> 9;
        int rem = idx & 511;
        int row = rem >> 3, ch8 = rem & 7;
        short8 v = *(const short8*)&ep[m2][row][ch8 * 8];
        if (m2 == 0)
            *(short8*)&Qb[(size_t)(r0 + row) * H_ + ch8 * 8] = v;
        else if (m2 == 1)
            *(short8*)&Kb[(size_t)(r0 + row) * H_ + ch8 * 8] = v;
        else   // row == V column here (ep[2] is transposed)
            *(short8*)&Vt[((size_t)(bb * 64 + row)) * T_ + rloc + ch8 * 8] = v;
    }
}

// ---------------------------------------------------------------------------
// Kernel 3: split-K flash attention (round-5 version, unchanged).
// ---------------------------------------------------------------------------
__global__ __launch_bounds__(256, 3) void attn_split_kernel(
    const unsigned short* __restrict__ Qb, const unsigned short* __restrict__ Kb,
    const unsigned short* __restrict__ Vt, unsigned short* __restrict__ Po,
    float* __restrict__ Pl)
{
    __shared__ unsigned short K_lds[2][64][64];   // 16 KB (two 8 KB buffers)
    __shared__ unsigned short V_lds[2][64][64];   // 16 KB
    __shared__ unsigned short p_lds[4][16][72];   // 9 KB, per-wave P round-trip
    const int tid   = threadIdx.x;
    const int wid   = tid >> 6, lane = tid & 63;
    const int g     = lane >> 4, c = lane & 15;

    const int s     = blockIdx.x * 4 + wid;      // [0, 8192)
    const int batch = s >> 11;
    const int rem   = s & 2047;
    const int ch    = rem >> 8;                  // kv-chunk [0,8)
    const int qt    = rem & 255;                 // q-tile   [0,256)
    const int nkv   = (qt >> 2) + 1;             // total kv tiles for this qt
    if (ch * 8 >= nkv) return;                   // whole block exits together
    const int nt    = min(8, nkv - ch * 8);      // tiles in this chunk (same all waves)
    const int qbase = qt * 16;
    const int lastt = nkv - 1 - ch * 8;          // local idx of diagonal tile

    const int Mm = nkv - 1, aa = Mm >> 3, rr8 = Mm & 7;
    const int npart = (nkv + 7) >> 3;
    const int slot  = batch * 1152 + 4 * (4 * aa * (aa + 1) + rr8 * (aa + 1))
                    + (qt & 3) * npart + ch;

    const int rsub = lane >> 3;                  // staging: row-in-8
    const int csw  = (lane & 7) ^ rsub;          // involution chunk swizzle
    const int cs0 = (g ^ (c & 7)) * 8;           // read chunk offsets (lane-const)
    const int cs1 = ((g + 4) ^ (c & 7)) * 8;

    short8 aq0, aq1;                             // Q fragments (pre-scaled)
    {
        const unsigned short* qp = Qb + ((size_t)(batch * T_ + qbase + c)) * H_ + 8 * g;
        aq0 = *(const short8*)&qp[0];
        aq1 = *(const short8*)&qp[32];
    }

    short8 ones;                                 // bf16 1.0 fragment for l-MFMA
    #pragma unroll
    for (int j = 0; j < 8; ++j) ones[j] = (short)0x3F80;

    f32x4 o_acc[4];
    #pragma unroll
    for (int n = 0; n < 4; ++n) o_acc[n] = 0.0f;
    f32x4 l_acc = 0.0f;

    auto stage = [&](int buf, int gt) {
        const int key0 = gt * 64;
        #pragma unroll
        for (int j = 0; j < 2; ++j) {
            const int row = wid * 16 + j * 8;
            const unsigned short* gk = Kb
                + ((size_t)(batch * T_ + key0 + row + rsub)) * H_ + csw * 8;
            __builtin_amdgcn_global_load_lds(
                (const GLOBAL_AS unsigned int*)gk,
                (LDS_AS unsigned int*)&K_lds[buf][row][0], 16, 0, 0);
            const unsigned short* gv = Vt
                + ((size_t)(batch * H_ + row + rsub)) * T_ + key0 + csw * 8;
            __builtin_amdgcn_global_load_lds(
                (const GLOBAL_AS unsigned int*)gv,
                (LDS_AS unsigned int*)&V_lds[buf][row][0], 16, 0, 0);
        }
    };

    stage(0, ch * 8);
    __syncthreads();

    for (int t = 0; t < nt; ++t) {
        const int buf = t & 1;
        if (t + 1 < nt) stage(buf ^ 1, ch * 8 + t + 1);

        // ---- S = Q K^T (K frags from LDS, swizzled chunks) ----
        f32x4 sA[4];
        #pragma unroll
        for (int n = 0; n < 4; ++n) sA[n] = 0.0f;
        #pragma unroll
        for (int n = 0; n < 4; ++n) {
            short8 bk0 = *(const short8*)&K_lds[buf][n * 16 + c][cs0];
            short8 bk1 = *(const short8*)&K_lds[buf][n * 16 + c][cs1];
            sA[n] = __builtin_amdgcn_mfma_f32_16x16x32_bf16(aq0, bk0, sA[n], 0, 0, 0);
            sA[n] = __builtin_amdgcn_mfma_f32_16x16x32_bf16(aq1, bk1, sA[n], 0, 0, 0);
        }

        // ---- p = exp2(s); mask only the diagonal tile ----
        float pv[4][4];
        #pragma unroll
        for (int n = 0; n < 4; ++n)
            #pragma unroll
            for (int r = 0; r < 4; ++r)
                pv[n][r] = EXP2(sA[n][r]);
        if (t == lastt) {                        // wave-uniform branch
            const int d = (ch * 8 + t) * 64 + c - qbase - 4 * g;
            #pragma unroll
            for (int n = 0; n < 4; ++n)
                #pragma unroll
                for (int r = 0; r < 4; ++r)
                    if (d + 16 * n > r) pv[n][r] = 0.0f;
        }

        // ---- P: D-layout -> A-frag layout via per-wave LDS ----
        #pragma unroll
        for (int n = 0; n < 4; ++n)
            #pragma unroll
            for (int r = 0; r < 4; ++r)
                p_lds[wid][4 * g + r][n * 16 + c] = f2bf(pv[n][r]);
        short8 pa0 = *(const short8*)&p_lds[wid][c][8 * g];
        short8 pa1 = *(const short8*)&p_lds[wid][c][32 + 8 * g];

        // ---- l += P * 1 ----
        l_acc = __builtin_amdgcn_mfma_f32_16x16x32_bf16(pa0, ones, l_acc, 0, 0, 0);
        l_acc = __builtin_amdgcn_mfma_f32_16x16x32_bf16(pa1, ones, l_acc, 0, 0, 0);

        // ---- O += P V (V frags from LDS, swizzled chunks) ----
        #pragma unroll
        for (int n = 0; n < 4; ++n) {
            short8 bv0 = *(const short8*)&V_lds[buf][n * 16 + c][cs0];
            short8 bv1 = *(const short8*)&V_lds[buf][n * 16 + c][cs1];
            o_acc[n] = __builtin_amdgcn_mfma_f32_16x16x32_bf16(pa0, bv0, o_acc[n], 0, 0, 0);
            o_acc[n] = __builtin_amdgcn_mfma_f32_16x16x32_bf16(pa1, bv1, o_acc[n], 0, 0, 0);
        }

        __syncthreads();
    }

    unsigned short* po = Po + (size_t)slot * 1024;
    #pragma unroll
    for (int n = 0; n < 4; ++n)
        #pragma unroll
        for (int r = 0; r < 4; ++r)
            po[(4 * g + r) * 64 + n * 16 + c] = f2bf(o_acc[n][r]);
    if (c == 0) {
        #pragma unroll
        for (int r = 0; r < 4; ++r)
            Pl[slot * 16 + 4 * g + r] = l_acc[r];
    }
}

// ---------------------------------------------------------------------------
// Kernel 4: merge partials — plain sums. One wave per q-tile.
// ---------------------------------------------------------------------------
__global__ __launch_bounds__(256) void attn_merge_kernel(
    const unsigned short* __restrict__ Po, const float* __restrict__ Pl,
    float* __restrict__ out)
{
    const int tid  = threadIdx.x;
    const int wid  = tid >> 6, lane = tid & 63;
    const int gi   = blockIdx.x * 4 + wid;       // [0, 1024)
    const int batch = gi >> 8, qt = gi & 255;
    const int nkv  = (qt >> 2) + 1;
    const int npart = (nkv + 7) >> 3;
    const int Mm = nkv - 1, aa = Mm >> 3, rr8 = Mm & 7;
    const int slot0 = batch * 1152 + 4 * (4 * aa * (aa + 1) + rr8 * (aa + 1))
                    + (qt & 3) * npart;

    const int row = lane & 15, seg = lane >> 4;

    float lacc = 0.0f, o[16];
    #pragma unroll
    for (int k = 0; k < 16; ++k) o[k] = 0.0f;

    for (int i = 0; i < npart; ++i) {
        lacc += Pl[(slot0 + i) * 16 + row];
        const unsigned short* pp = Po + (size_t)(slot0 + i) * 1024 + row * 64 + seg * 16;
        short8 v0 = *(const short8*)&pp[0];
        short8 v1 = *(const short8*)&pp[8];
        #pragma unroll
        for (int k = 0; k < 8; ++k) {
            o[k]     += bf2f((unsigned short)v0[k]);
            o[8 + k] += bf2f((unsigned short)v1[k]);
        }
    }

    const float inv = 1.0f / lacc;
    float* op = out + ((size_t)(batch * T_ + qt * 16 + row)) * H_ + seg * 16;
    #pragma unroll
    for (int k = 0; k < 16; ++k) op[k] = o[k] * inv;
}

// ---------------------------------------------------------------------------
extern "C" void kernel_launch(void* const* d_in, const int* in_sizes, int n_in,
                              void* d_out, int out_size, void* d_ws, size_t ws_size,
                              hipStream_t stream)
{
    const float* x  = (const float*)d_in[0];
    const float* Wk = (const float*)d_in[1];
    const float* Wq = (const float*)d_in[2];
    const float* Wv = (const float*)d_in[3];
    float* out = (float*)d_out;

    // workspace layout:
    //   Wt  [3*64*1024] bf16            384 KB
    //   Qb/Kb [B*T*H] bf16            2+2 MB
    //   Vt  [B*H*T] bf16                  2 MB
    //   Po  [4608][16][64] bf16         9.4 MB
    //   Pl  [4608][16] f32              295 KB   total ~16.1 MB
    unsigned short* Wt = (unsigned short*)d_ws;
    unsigned short* Qb = Wt + 3 * 64 * 1024;
    unsigned short* Kb = Qb + (size_t)B_ * T_ * H_;
    unsigned short* Vt = Kb + (size_t)B_ * T_ * H_;
    unsigned short* Po = Vt + (size_t)B_ * T_ * H_;
    float* Pl = (float*)(Po + (size_t)4608 * 1024);

    hipLaunchKernelGGL(wt_transpose_kernel, dim3(48), dim3(256), 0, stream, Wq, Wk, Wv, Wt);
    hipLaunchKernelGGL(proj_kernel, dim3(256), dim3(768), 0, stream, x, Wt, Qb, Kb, Vt);
    hipLaunchKernelGGL(attn_split_kernel, dim3(2048), dim3(256), 0, stream, Qb, Kb, Vt, Po, Pl);
    hipLaunchKernelGGL(attn_merge_kernel, dim3(256), dim3(256), 0, stream, Po, Pl, out);
}